// Round 1
// 262.334 us; speedup vs baseline: 1.0009x; 1.0009x over previous
//
#include <hip/hip_runtime.h>
#include <hip/hip_bf16.h>
#include <cstdint>
#include <type_traits>

typedef __attribute__((ext_vector_type(8))) __bf16 bf16x8;
typedef __attribute__((ext_vector_type(4))) float f32x4;
typedef __attribute__((ext_vector_type(2))) long longx2;

struct bf2frag { bf16x8 k0, k1; };

__device__ __forceinline__ float bf2f(unsigned short u) {
  union { uint32_t i; float f; } v; v.i = (uint32_t)u << 16; return v.f;
}
__device__ __forceinline__ unsigned short f2bf(float f) {
  union { float f; uint32_t i; } v{f};
  uint32_t r = v.i + 0x7fffu + ((v.i >> 16) & 1u);
  return (unsigned short)(r >> 16);
}

__device__ __forceinline__ void gll(const void* g, void* l) {
  __builtin_amdgcn_global_load_lds(
      (const __attribute__((address_space(1))) uint32_t*)(uintptr_t)g,
      (__attribute__((address_space(3))) uint32_t*)(uint32_t)(uintptr_t)l,
      16, 0, 0);
}

__device__ __forceinline__ void bar() {
  asm volatile("" ::: "memory");
  __builtin_amdgcn_s_barrier();
  asm volatile("" ::: "memory");
}

#define VMCNT(n) asm volatile("s_waitcnt vmcnt(" #n ")" ::: "memory")

template <int N>
__device__ __forceinline__ void vmw() {
  if constexpr (N == 0) { VMCNT(0); }
  else if constexpr (N == 1) { VMCNT(1); }
  else if constexpr (N == 2) { VMCNT(2); }
  else if constexpr (N == 3) { VMCNT(3); }
  else if constexpr (N == 4) { VMCNT(4); }
  else if constexpr (N == 5) { VMCNT(5); }
  else if constexpr (N == 6) { VMCNT(6); }
  else if constexpr (N == 7) { VMCNT(7); }
  else if constexpr (N == 8) { VMCNT(8); }
  else if constexpr (N == 9) { VMCNT(9); }
  else if constexpr (N == 10) { VMCNT(10); }
  else { VMCNT(12); }
}

__device__ __forceinline__ f32x4 mma(bf16x8 a, bf16x8 b, f32x4 c) {
  return __builtin_amdgcn_mfma_f32_16x16x32_bf16(a, b, c, 0, 0, 0);
}
__device__ __forceinline__ f32x4 mma(long a, long b, f32x4 c) {
  return __builtin_amdgcn_mfma_f32_16x16x32_fp8_fp8(a, b, c, 0, 0, 0);
}
__device__ __forceinline__ f32x4 mmak(const bf2frag& a, const bf2frag& b, f32x4 c, int k2) {
  return k2 ? mma(a.k1, b.k1, c) : mma(a.k0, b.k0, c);
}
__device__ __forceinline__ f32x4 mmak(longx2 a, longx2 b, f32x4 c, int k2) {
  return mma(a[k2], b[k2], c);
}

// k-interleave store permutation for fp8 buffers (unit u=8B: slot p(u)=(u&3)*2+(u>>2))
__device__ __forceinline__ int perm64(int m) {
  return (m & ~63) | (((m >> 3) & 3) << 4) | (((m >> 5) & 1) << 3) | (m & 7);
}

// ---------------- GroupNorm stats ----------------
__global__ __launch_bounds__(256) void stats_partial_k(const float* __restrict__ x,
                                                       float* __restrict__ part) {
  const int g = blockIdx.x >> 3, p = blockIdx.x & 7;
  const float* base = x + (long)g * 16 * 18432 + (long)p * 2304;
  float s = 0.f, ss = 0.f;
  for (int idx = threadIdx.x; idx < 16 * 576; idx += 256) {
    const int c = idx / 576, i4 = idx % 576;
    const float4 v = *(const float4*)(base + (long)c * 18432 + i4 * 4);
    s += v.x + v.y + v.z + v.w;
    ss += v.x * v.x + v.y * v.y + v.z * v.z + v.w * v.w;
  }
  __shared__ float rs[256], rss[256];
  rs[threadIdx.x] = s; rss[threadIdx.x] = ss;
  __syncthreads();
  for (int o = 128; o > 0; o >>= 1) {
    if ((int)threadIdx.x < o) { rs[threadIdx.x] += rs[threadIdx.x + o]; rss[threadIdx.x] += rss[threadIdx.x + o]; }
    __syncthreads();
  }
  if (threadIdx.x == 0) { part[blockIdx.x * 2] = rs[0]; part[blockIdx.x * 2 + 1] = rss[0]; }
}

__global__ void stats_final_k(const float* __restrict__ part, float* __restrict__ stats) {
  const int g = threadIdx.x;
  if (g < 32) {
    float s = 0.f, ss = 0.f;
    for (int p = 0; p < 8; ++p) { s += part[(g * 8 + p) * 2]; ss += part[(g * 8 + p) * 2 + 1]; }
    const float mean = s / 294912.0f;
    const float var = ss / 294912.0f - mean * mean;
    stats[g * 2] = mean;
    stats[g * 2 + 1] = rsqrtf(var + 1e-6f);
  }
}

// ---------------- GN apply + transpose to (spatial, channel) bf16 ----------------
__global__ __launch_bounds__(256) void gn_transpose_k(const float* __restrict__ x,
                                                      const float* __restrict__ stats,
                                                      const float* __restrict__ gamma,
                                                      const float* __restrict__ beta,
                                                      unsigned short* __restrict__ hnT) {
  __shared__ float tile[64][65];
  const int c0 = blockIdx.x * 64, n0 = blockIdx.y * 64;
  const int tn = threadIdx.x & 63, tr = threadIdx.x >> 6;
  for (int cc = tr; cc < 64; cc += 4) {
    const int c = c0 + cc, g = c >> 4;
    const float mean = stats[g * 2], rstd = stats[g * 2 + 1];
    const float v = x[(long)c * 18432 + n0 + tn];
    tile[cc][tn] = (v - mean) * rstd * gamma[c] + beta[c];
  }
  __syncthreads();
  for (int nn = tr; nn < 64; nn += 4) {
    hnT[(long)(n0 + nn) * 512 + c0 + tn] = f2bf(tile[tn][nn]);
  }
}

// ---------------- fp32 -> bf16 weight pack ----------------
__global__ __launch_bounds__(256) void pack_bf16_k(const float* __restrict__ w,
                                                   unsigned short* __restrict__ o) {
  const int i = (blockIdx.x * 256 + threadIdx.x) * 4;
  const float4 v = *(const float4*)(w + i);
  ushort4 u; u.x = f2bf(v.x); u.y = f2bf(v.y); u.z = f2bf(v.z); u.w = f2bf(v.w);
  *(ushort4*)(o + i) = u;
}

__global__ void pack_bias_k(const float* __restrict__ bq, const float* __restrict__ bk,
                            float* __restrict__ bqk) {
  const int t = threadIdx.x;
  bqk[t] = (t < 512) ? bq[t] : bk[t - 512];
}

// ---------------- per-row 1/L combine from per-tile sums (NT tiles of 128 rows) ----------------
__global__ __launch_bounds__(256) void combine_k(const float* __restrict__ rs,
                                                 float* __restrict__ linv, int ntile) {
  const int row = blockIdx.x * 256 + threadIdx.x;  // [0, 18432)
  const int t = row / 2304, r = row % 2304;
  float L = 0.f;
  for (int x = 0; x < ntile; ++x) L += rs[((long)(t * ntile + x)) * 2304 + r];
  linv[row] = 1.0f / L;
}

// ================= BMx256x64 NT GEMM, XCD-swizzled, bf16/fp8 =================
// C[n*ldc+m] = alpha*sum_k A[m,k]*B[n,k] (+bias)(+resid)
// BM=256: 512 thr, 8 waves (2m x 4n), 1 block/CU (regs: 128 acc + ~96 -> 2 waves/SIMD cap).
// BM=128: 256 thr, 4 waves (1m x 4n); fp8 -> 48KB LDS, ~224 regs/wave ->
//   2 blocks/CU co-resident: independent barrier groups overlap each other's
//   stage/vmcnt stalls (PV-proven in R9; applied to S).
// P2=0 (8-phase snake): (m0,n0)->(m0,n1)->(m1,n1)->(m1,n0); A-half reused 2 phases.
//   Stages: p0:A0(W+1)->s^1  p1:B1(W+1)->s^1  p2:B0(W+2)->s  p3:A1(W+2)->s.
//   Prologue: [B0(0),A0(0),B1(0),A1(0),B0(1),A1(1)].
//   vmcnt (gll units): V0=GB+2GA @p0-end, V3=2GB+GA @p3-end, VP=GB+GA prologue.
// P2=1 (2-phase, 4 barriers/K-step -- R10: target barrier-sync jitter on short-K fp8):
//   P0: read A0,B0,B1; stage [A0,B1,A1](W+1)->s^1 (A1 LAST); mfma (m0 x n0,n1).
//   P1: read A1; stage B0(W+2)->s; mfma (m1 x n1,n0).
//   FIFO-derived waits: @P0-end vmcnt(2GA+2GB) (drains A1(W)); @P1-end vmcnt(GA+GB)
//   (drains A0/B1(W+1) trio head + B0(W+1)); tail: P1-end GA when st2 off, 0 last.
//   Prologue: [B0(0),A0(0),B1(0),A1(0),B0(1)]  (A1(1) moves into W0-P0 trio).
//   Hazard note: A1(W+2) may NOT be staged in the same phase that reads A1(W)
//   (no lgkm-forcing point between cross-wave read/overwrite) -- hence trio in P0.
// STATS scratch: NSLOT = waves-per-n-column (8 for BM=256, 4 for BM=128).
// OUT_MODE: 0 bf16, 1 f32+resid, 2 fp8 e4m3 k-interleaved. STATS: exp+rowsums.
// SCALEN: *linv[n]. MODE0: bz=bid%8 per XCD; MODE1/2: XCD y/x-chunking.
template <int BM, int BIAS_MODE, int OUT_MODE, int STATS, int SCALEN, int MODE, int FP8, int P2>
__global__ __launch_bounds__(512, 2) void gemm256(const void* __restrict__ A, long lda, long sAz,
                                                  const void* __restrict__ B, long ldb, long sBz,
                                                  void* __restrict__ Cp, long ldc, long sCz,
                                                  const float* __restrict__ bias,
                                                  const float* __restrict__ resid,
                                                  float* __restrict__ rowsums,
                                                  const float* __restrict__ linv,
                                                  float alpha, int K, int gx, int gy) {
  constexpr int EB = FP8 ? 1 : 2;                    // element bytes
  constexpr int THREADS = (BM == 256) ? 512 : 256;
  constexpr int HBA = (BM / 2) * 64 * EB;            // bytes per A half
  constexpr int HBB = 128 * 64 * EB;                 // bytes per B half
  constexpr int GA = HBA / (THREADS * 16);           // gll per A-half stage
  constexpr int GB = HBB / (THREADS * 16);           // gll per B-half stage
  constexpr int V0 = GB + 2 * GA, V3 = 2 * GB + GA, VP = GB + GA;
  constexpr int NSLOT = (BM == 256) ? 8 : 4;
  __shared__ alignas(16) unsigned char As[2][2][HBA];
  __shared__ alignas(16) unsigned char Bs[2][2][HBB];
  using ABt2 = typename std::conditional<FP8, longx2, bf2frag>::type;

  const int tid = threadIdx.x;
  const int lane = tid & 63, wid = tid >> 6;
  const int wm = (BM == 256) ? (wid & 1) : 0;
  const int wn = (BM == 256) ? (wid >> 1) : wid;
  int bx, by, bz;
  {
    const int g8 = blockIdx.x & 7, n = blockIdx.x >> 3;
    if (MODE == 0) { bz = g8; bx = n % gx; by = n / gx; }
    else if (MODE == 1) { bz = 0; bx = n % gx; by = g8 * gy + n / gx; }
    else { bz = 0; by = n % gy; bx = g8 * gx + n / gy; }
  }
  const unsigned char* Ab = (const unsigned char*)A + ((long)bz * sAz + (long)bx * BM * lda) * EB;
  const unsigned char* Bb = (const unsigned char*)B + ((long)bz * sBz + (long)by * 256 * ldb) * EB;

  // ---- staging (global -> LDS, pre-swizzled source; fp8 global is k-interleaved) ----
  auto stageA = [&](int slot, int h, int k0) {
    if constexpr (!FP8) {
      const int ksw = ((tid & 7) << 3) ^ (((tid >> 3) & 7) << 3);
#pragma unroll
      for (int call = 0; call < GA; ++call) {
        const int r = call * (THREADS / 8) + (tid >> 3);
        const int grow = ((r >> 6) << 7) + h * 64 + (r & 63);
        gll(Ab + ((long)grow * lda + k0) * 2 + ksw * 2, &As[slot][h][call * THREADS * 16 + tid * 16]);
      }
    } else {
#pragma unroll
      for (int call = 0; call < GA; ++call) {
        const int l = call * (THREADS / 4) + (tid >> 2);
        const int grow = ((l >> 6) << 7) + h * 64 + (l & 63);
        const int x = (((l & 3) ^ ((l >> 2) & 3)) << 4);
        gll(Ab + (long)grow * lda + k0 + (((tid & 3) << 4) ^ x),
            &As[slot][h][call * THREADS * 16 + tid * 16]);
      }
    }
  };
  auto stageB = [&](int slot, int h, int k0) {
    if constexpr (!FP8) {
      const int ksw = ((tid & 7) << 3) ^ (((tid >> 3) & 7) << 3);
#pragma unroll
      for (int call = 0; call < GB; ++call) {
        const int r = call * (THREADS / 8) + (tid >> 3);
        const int grow = ((r >> 5) << 6) + h * 32 + (r & 31);
        gll(Bb + ((long)grow * ldb + k0) * 2 + ksw * 2, &Bs[slot][h][call * THREADS * 16 + tid * 16]);
      }
    } else {
#pragma unroll
      for (int call = 0; call < GB; ++call) {
        const int l = call * (THREADS / 4) + (tid >> 2);
        const int grow = ((l >> 5) << 6) + h * 32 + (l & 31);
        const int x = (((l & 3) ^ ((l >> 2) & 3)) << 4);
        gll(Bb + (long)grow * ldb + k0 + (((tid & 3) << 4) ^ x),
            &Bs[slot][h][call * THREADS * 16 + tid * 16]);
      }
    }
  };
  // ---- LDS -> fragment reads (same swizzle; fp8 = ONE b128 for both k2 slices) ----
  auto ldA = [&](int slot, int mh, int fq) -> ABt2 {
    const int r = wm * 64 + fq * 16 + (lane & 15);
    if constexpr (!FP8) {
      bf2frag f;
      const int kk0 = (((lane >> 4) << 3)) ^ ((r & 7) << 3);
      const int kk1 = (32 + ((lane >> 4) << 3)) ^ ((r & 7) << 3);
      f.k0 = *reinterpret_cast<const bf16x8*>(&As[slot][mh][r * 128 + kk0 * 2]);
      f.k1 = *reinterpret_cast<const bf16x8*>(&As[slot][mh][r * 128 + kk1 * 2]);
      return f;
    } else {
      const int x = (((r & 3) ^ ((r >> 2) & 3)) << 4);
      const int kk = ((lane >> 4) << 4) ^ x;
      return *reinterpret_cast<const longx2*>(&As[slot][mh][r * 64 + kk]);
    }
  };
  auto ldB = [&](int slot, int nh, int g) -> ABt2 {
    const int r = wn * 32 + g * 16 + (lane & 15);
    if constexpr (!FP8) {
      bf2frag f;
      const int kk0 = (((lane >> 4) << 3)) ^ ((r & 7) << 3);
      const int kk1 = (32 + ((lane >> 4) << 3)) ^ ((r & 7) << 3);
      f.k0 = *reinterpret_cast<const bf16x8*>(&Bs[slot][nh][r * 128 + kk0 * 2]);
      f.k1 = *reinterpret_cast<const bf16x8*>(&Bs[slot][nh][r * 128 + kk1 * 2]);
      return f;
    } else {
      const int x = (((r & 3) ^ ((r >> 2) & 3)) << 4);
      const int kk = ((lane >> 4) << 4) ^ x;
      return *reinterpret_cast<const longx2*>(&Bs[slot][nh][r * 64 + kk]);
    }
  };

  f32x4 acc[8][4] = {};
  ABt2 a[4], b0[2], b1[2];

#define READ_A(SLOT, MH)                                                     \
  _Pragma("unroll") for (int fq = 0; fq < 4; ++fq) a[fq] = ldA(SLOT, MH, fq);
#define READ_B(SLOT, NH, DST)                                                \
  _Pragma("unroll") for (int g = 0; g < 2; ++g) DST[g] = ldB(SLOT, NH, g);
#define MFMA_QUAD(MH, NH, BARR)                                              \
  __builtin_amdgcn_s_setprio(1);                                             \
  _Pragma("unroll") for (int fq = 0; fq < 4; ++fq)                           \
    _Pragma("unroll") for (int g = 0; g < 2; ++g)                            \
      _Pragma("unroll") for (int k2 = 0; k2 < 2; ++k2)                       \
        acc[(MH) * 4 + fq][(NH) * 2 + g] =                                   \
            mmak(a[fq], BARR[g], acc[(MH) * 4 + fq][(NH) * 2 + g], k2);      \
  __builtin_amdgcn_s_setprio(0);

  const int KT = K >> 6;
  // Prologue queue: [B0(0), A0(0), B1(0), A1(0), B0(1)] (+A1(1) for P2=0)
  stageB(0, 0, 0);
  stageA(0, 0, 0);
  stageB(0, 1, 0);
  stageA(0, 1, 0);
  stageB(1, 0, 64);
  if constexpr (!P2) stageA(1, 1, 64);
  vmw<VP>();
  bar();

  if constexpr (!P2) {
    for (int W = 0; W < KT; ++W) {
      const int s = W & 1;
      const int kn1 = (W + 1) << 6, kn2 = (W + 2) << 6;
      const bool st1 = (W + 1 < KT), st2 = (W + 2 < KT);
      // p0: (m0,n0)
      READ_A(s, 0)
      READ_B(s, 0, b0)
      if (st1) stageA(s ^ 1, 0, kn1);
      bar();
      MFMA_QUAD(0, 0, b0)
      if (st1) { vmw<V0>(); }
      bar();
      // p1: (m0,n1)
      READ_B(s, 1, b1)
      if (st1) stageB(s ^ 1, 1, kn1);
      bar();
      MFMA_QUAD(0, 1, b1)
      bar();
      // p2: (m1,n1)
      READ_A(s, 1)
      if (st2) stageB(s, 0, kn2);
      bar();
      MFMA_QUAD(1, 1, b1)
      bar();
      // p3: (m1,n0)
      if (st2) stageA(s, 1, kn2);
      bar();
      MFMA_QUAD(1, 0, b0)
      if (st2) { vmw<V3>(); } else { vmw<0>(); }
      bar();
    }
  } else {
    for (int W = 0; W < KT; ++W) {
      const int s = W & 1;
      const int kn1 = (W + 1) << 6, kn2 = (W + 2) << 6;
      const bool st1 = (W + 1 < KT), st2 = (W + 2 < KT);
      // P0: (m0 x n0,n1); stage next A-slot fully + B1(W+1). A1 issued LAST.
      READ_A(s, 0)
      READ_B(s, 0, b0)
      READ_B(s, 1, b1)
      if (st1) { stageA(s ^ 1, 0, kn1); stageB(s ^ 1, 1, kn1); stageA(s ^ 1, 1, kn1); }
      bar();
      MFMA_QUAD(0, 0, b0)
      MFMA_QUAD(0, 1, b1)
      if (st1) { vmw<2 * (GA + GB)>(); } else { vmw<0>(); }
      bar();
      // P1: (m1 x n1,n0); stage B0(W+2) into current slot (B0(W) consumed in P0).
      READ_A(s, 1)
      if (st2) stageB(s, 0, kn2);
      bar();
      MFMA_QUAD(1, 1, b1)
      MFMA_QUAD(1, 0, b0)
      if (st2) { vmw<GA + GB>(); } else if (st1) { vmw<GA>(); } else { vmw<0>(); }
      bar();
    }
  }

  // epilogue: acc[M][N], M = mh*4+fq (m-off = mh*64+fq*16), N = nh*2+g
  const int mg0 = bx * BM + wm * 128 + ((lane >> 4) << 2);
  const int ng0 = by * 256 + wn * 64 + (lane & 15);
  float* red = (float*)&As[0][0][0];  // STATS scratch: 256 rows x NSLOT f32
#pragma unroll
  for (int N = 0; N < 4; ++N) {
    const int n = ng0 + (N >> 1) * 32 + (N & 1) * 16;
    const float bn = (BIAS_MODE == 2) ? bias[n] : 0.f;
    const float sc = SCALEN ? linv[(long)bz * 2304 + n] : 1.0f;
    float eN = 0.f;
#pragma unroll
    for (int M = 0; M < 8; ++M) {
      const int m = mg0 + (M >> 2) * 64 + (M & 3) * 16;
      const f32x4 av = acc[M][N];
      float vals[4];
#pragma unroll
      for (int j = 0; j < 4; ++j) {
        vals[j] = av[j] * alpha + ((BIAS_MODE == 1) ? bias[m + j] : bn);
        if (SCALEN) vals[j] *= sc;
        if (STATS) { vals[j] = __expf(vals[j]); eN += vals[j]; }
      }
      if (OUT_MODE == 0) {
        ushort4 o; o.x = f2bf(vals[0]); o.y = f2bf(vals[1]); o.z = f2bf(vals[2]); o.w = f2bf(vals[3]);
        *(ushort4*)((unsigned short*)Cp + (long)bz * sCz + (long)n * ldc + m) = o;
      } else if (OUT_MODE == 2) {
        int pk = __builtin_amdgcn_cvt_pk_fp8_f32(vals[0], vals[1], 0, false);
        pk = __builtin_amdgcn_cvt_pk_fp8_f32(vals[2], vals[3], pk, true);
        *(int*)((unsigned char*)Cp + (long)bz * sCz + (long)n * ldc + perm64(m)) = pk;
      } else {
        const float* rp = resid + (long)n * ldc + m;
        float4 o; o.x = vals[0] + rp[0]; o.y = vals[1] + rp[1]; o.z = vals[2] + rp[2]; o.w = vals[3] + rp[3];
        *(float4*)((float*)Cp + (long)bz * sCz + (long)n * ldc + m) = o;
      }
    }
    if (STATS) {
      const int nloc = wn * 64 + (N >> 1) * 32 + (N & 1) * 16 + (lane & 15);
      const int slot = wm * 4 + (lane >> 4);
      red[nloc * NSLOT + slot] = eN;
    }
  }
  if (STATS) {
    bar();
    if (tid < 256) {
      float L = 0.f;
#pragma unroll
      for (int s2 = 0; s2 < NSLOT; ++s2) L += red[tid * NSLOT + s2];
      rowsums[((long)(bz * gx + bx)) * 2304 + by * 256 + tid] = L;
    }
  }
#undef READ_A
#undef READ_B
#undef MFMA_QUAD
}

extern "C" void kernel_launch(void* const* d_in, const int* in_sizes, int n_in,
                              void* d_out, int out_size, void* d_ws, size_t ws_size,
                              hipStream_t stream) {
  const float* x = (const float*)d_in[0];
  const float* gamma = (const float*)d_in[1];
  const float* beta = (const float*)d_in[2];
  const float* wq = (const float*)d_in[3];
  const float* bq = (const float*)d_in[4];
  const float* wk = (const float*)d_in[5];
  const float* bk = (const float*)d_in[6];
  const float* wv = (const float*)d_in[7];
  const float* bv = (const float*)d_in[8];
  const float* wo = (const float*)d_in[9];
  const float* bo = (const float*)d_in[10];
  float* out = (float*)d_out;

  char* ws = (char*)d_ws;
  size_t off = 0;
  auto alloc = [&](size_t bytes) {
    char* p = ws + off;
    off = (off + bytes + 255) & ~(size_t)255;
    return p;
  };
  float* part = (float*)alloc(256 * 2 * sizeof(float));
  float* stats = (float*)alloc(32 * 2 * sizeof(float));
  unsigned short* wqkb = (unsigned short*)alloc((size_t)2 * 262144 * 2);
  unsigned short* wvb = (unsigned short*)alloc((size_t)262144 * 2);
  unsigned short* wob = (unsigned short*)alloc((size_t)262144 * 2);
  float* bqk = (float*)alloc(1024 * sizeof(float));
  float* rowsums = (float*)alloc((size_t)8 * 18 * 2304 * sizeof(float));
  float* linv = (float*)alloc((size_t)18432 * sizeof(float));
  unsigned short* hnT = (unsigned short*)alloc((size_t)18432 * 512 * 2);
  unsigned char* qkA = (unsigned char*)alloc((size_t)18432 * 1024);      // fp8 k-interleaved
  unsigned char* vT = (unsigned char*)alloc((size_t)512 * 18432);        // fp8 k-interleaved
  unsigned char* Sm = (unsigned char*)alloc((size_t)8 * 2304 * 2304);    // fp8 E k-interleaved
  unsigned short* Ob = hnT;  // alias: hnT fully consumed after qk/v GEMMs
  (void)ws_size; (void)in_sizes; (void)n_in; (void)out_size;

  stats_partial_k<<<dim3(256), dim3(256), 0, stream>>>(x, part);
  stats_final_k<<<dim3(1), dim3(64), 0, stream>>>(part, stats);
  gn_transpose_k<<<dim3(8, 288), dim3(256), 0, stream>>>(x, stats, gamma, beta, hnT);
  pack_bf16_k<<<dim3(256), dim3(256), 0, stream>>>(wq, wqkb);
  pack_bf16_k<<<dim3(256), dim3(256), 0, stream>>>(wk, wqkb + 262144);
  pack_bf16_k<<<dim3(256), dim3(256), 0, stream>>>(wv, wvb);
  pack_bf16_k<<<dim3(256), dim3(256), 0, stream>>>(wo, wob);
  pack_bias_k<<<dim3(1), dim3(1024), 0, stream>>>(bq, bk, bqk);

  // qk fused: A=[Wq;Wk] bf16, B=hnT bf16 -> q,k fp8 interleaved [sp][1024]. MODE1: 288 blocks.
  gemm256<256, 1, 2, 0, 0, 1, 0, 0><<<dim3(288), dim3(512), 0, stream>>>(
      wqkb, 512, 0, hnT, 512, 0, (void*)qkA, 1024, 0, bqk, nullptr, nullptr, nullptr,
      1.0f, 512, 4, 9);
  // v: A=hnT bf16, B=Wv bf16 -> vT fp8 interleaved [co][18432]. MODE2: 144 blocks.
  gemm256<256, 2, 2, 0, 0, 2, 0, 0><<<dim3(144), dim3(512), 0, stream>>>(
      hnT, 512, 0, wvb, 512, 0, (void*)vT, 18432, 0, bv, nullptr, nullptr, nullptr,
      1.0f, 512, 9, 2);
  // S: per t: A=k fp8, B=q fp8 -> E=exp(alpha*S) fp8 interleaved + rowsums.
  // BM=128 (256 thr, 2 blocks/CU), P2=1 (2-phase, 4 barriers/K-step): 1296 blocks MODE0.
  gemm256<128, 0, 2, 1, 0, 0, 1, 1><<<dim3(1296), dim3(256), 0, stream>>>(
      qkA + 512, 1024, (long)2304 * 1024, qkA, 1024, (long)2304 * 1024, (void*)Sm, 2304,
      (long)2304 * 2304, nullptr, nullptr, rowsums, nullptr,
      0.044194173824159216f, 512, 18, 9);
  combine_k<<<dim3(72), dim3(256), 0, stream>>>(rowsums, linv, 18);
  // PV: per t: A=vT fp8, B=E fp8 -> O bf16 [(t,i)*512+c], rows scaled by linv.
  // BM=128 (256 thr, 2 blocks/CU), P2=1: 288 blocks MODE0.
  gemm256<128, 0, 0, 0, 1, 0, 1, 1><<<dim3(288), dim3(256), 0, stream>>>(
      vT, 18432, 2304, Sm, 2304, (long)2304 * 2304, (void*)Ob, 512, (long)2304 * 512,
      nullptr, nullptr, nullptr, linv, 1.0f, 2304, 4, 0);
  // final: A=O bf16, B=Wo bf16 -> out[co*18432+sp] = x + acc + bo[co]. MODE2: 144 blocks.
  gemm256<256, 2, 1, 0, 0, 2, 0, 0><<<dim3(144), dim3(512), 0, stream>>>(
      Ob, 512, 0, wob, 512, 0, (void*)out, 18432, 0, bo, x, nullptr, nullptr,
      1.0f, 512, 9, 2);
}

// Round 2
// 261.228 us; speedup vs baseline: 1.0051x; 1.0042x over previous
//
#include <hip/hip_runtime.h>
#include <hip/hip_bf16.h>
#include <cstdint>
#include <type_traits>

typedef __attribute__((ext_vector_type(8))) __bf16 bf16x8;
typedef __attribute__((ext_vector_type(4))) float f32x4;
typedef __attribute__((ext_vector_type(2))) long longx2;

struct bf2frag { bf16x8 k0, k1; };

__device__ __forceinline__ float bf2f(unsigned short u) {
  union { uint32_t i; float f; } v; v.i = (uint32_t)u << 16; return v.f;
}
__device__ __forceinline__ unsigned short f2bf(float f) {
  union { float f; uint32_t i; } v{f};
  uint32_t r = v.i + 0x7fffu + ((v.i >> 16) & 1u);
  return (unsigned short)(r >> 16);
}

__device__ __forceinline__ void gll(const void* g, void* l) {
  __builtin_amdgcn_global_load_lds(
      (const __attribute__((address_space(1))) uint32_t*)(uintptr_t)g,
      (__attribute__((address_space(3))) uint32_t*)(uint32_t)(uintptr_t)l,
      16, 0, 0);
}

__device__ __forceinline__ void bar() {
  asm volatile("" ::: "memory");
  __builtin_amdgcn_s_barrier();
  asm volatile("" ::: "memory");
}

#define VMCNT(n) asm volatile("s_waitcnt vmcnt(" #n ")" ::: "memory")

template <int N>
__device__ __forceinline__ void vmw() {
  if constexpr (N == 0) { VMCNT(0); }
  else if constexpr (N == 1) { VMCNT(1); }
  else if constexpr (N == 2) { VMCNT(2); }
  else if constexpr (N == 3) { VMCNT(3); }
  else if constexpr (N == 4) { VMCNT(4); }
  else if constexpr (N == 5) { VMCNT(5); }
  else if constexpr (N == 6) { VMCNT(6); }
  else if constexpr (N == 7) { VMCNT(7); }
  else if constexpr (N == 8) { VMCNT(8); }
  else if constexpr (N == 9) { VMCNT(9); }
  else if constexpr (N == 10) { VMCNT(10); }
  else { VMCNT(12); }
}

__device__ __forceinline__ f32x4 mma(bf16x8 a, bf16x8 b, f32x4 c) {
  return __builtin_amdgcn_mfma_f32_16x16x32_bf16(a, b, c, 0, 0, 0);
}
__device__ __forceinline__ f32x4 mma(long a, long b, f32x4 c) {
  return __builtin_amdgcn_mfma_f32_16x16x32_fp8_fp8(a, b, c, 0, 0, 0);
}
__device__ __forceinline__ f32x4 mmak(const bf2frag& a, const bf2frag& b, f32x4 c, int k2) {
  return k2 ? mma(a.k1, b.k1, c) : mma(a.k0, b.k0, c);
}
__device__ __forceinline__ f32x4 mmak(longx2 a, longx2 b, f32x4 c, int k2) {
  return mma(a[k2], b[k2], c);
}

// k-interleave store permutation for fp8 buffers (unit u=8B: slot p(u)=(u&3)*2+(u>>2))
__device__ __forceinline__ int perm64(int m) {
  return (m & ~63) | (((m >> 3) & 3) << 4) | (((m >> 5) & 1) << 3) | (m & 7);
}

// ---------------- GroupNorm stats ----------------
__global__ __launch_bounds__(256) void stats_partial_k(const float* __restrict__ x,
                                                       float* __restrict__ part) {
  const int g = blockIdx.x >> 3, p = blockIdx.x & 7;
  const float* base = x + (long)g * 16 * 18432 + (long)p * 2304;
  float s = 0.f, ss = 0.f;
  for (int idx = threadIdx.x; idx < 16 * 576; idx += 256) {
    const int c = idx / 576, i4 = idx % 576;
    const float4 v = *(const float4*)(base + (long)c * 18432 + i4 * 4);
    s += v.x + v.y + v.z + v.w;
    ss += v.x * v.x + v.y * v.y + v.z * v.z + v.w * v.w;
  }
  __shared__ float rs[256], rss[256];
  rs[threadIdx.x] = s; rss[threadIdx.x] = ss;
  __syncthreads();
  for (int o = 128; o > 0; o >>= 1) {
    if ((int)threadIdx.x < o) { rs[threadIdx.x] += rs[threadIdx.x + o]; rss[threadIdx.x] += rss[threadIdx.x + o]; }
    __syncthreads();
  }
  if (threadIdx.x == 0) { part[blockIdx.x * 2] = rs[0]; part[blockIdx.x * 2 + 1] = rss[0]; }
}

__global__ void stats_final_k(const float* __restrict__ part, float* __restrict__ stats) {
  const int g = threadIdx.x;
  if (g < 32) {
    float s = 0.f, ss = 0.f;
    for (int p = 0; p < 8; ++p) { s += part[(g * 8 + p) * 2]; ss += part[(g * 8 + p) * 2 + 1]; }
    const float mean = s / 294912.0f;
    const float var = ss / 294912.0f - mean * mean;
    stats[g * 2] = mean;
    stats[g * 2 + 1] = rsqrtf(var + 1e-6f);
  }
}

// ---------------- GN apply + transpose to (spatial, channel) bf16 ----------------
__global__ __launch_bounds__(256) void gn_transpose_k(const float* __restrict__ x,
                                                      const float* __restrict__ stats,
                                                      const float* __restrict__ gamma,
                                                      const float* __restrict__ beta,
                                                      unsigned short* __restrict__ hnT) {
  __shared__ float tile[64][65];
  const int c0 = blockIdx.x * 64, n0 = blockIdx.y * 64;
  const int tn = threadIdx.x & 63, tr = threadIdx.x >> 6;
  for (int cc = tr; cc < 64; cc += 4) {
    const int c = c0 + cc, g = c >> 4;
    const float mean = stats[g * 2], rstd = stats[g * 2 + 1];
    const float v = x[(long)c * 18432 + n0 + tn];
    tile[cc][tn] = (v - mean) * rstd * gamma[c] + beta[c];
  }
  __syncthreads();
  for (int nn = tr; nn < 64; nn += 4) {
    hnT[(long)(n0 + nn) * 512 + c0 + tn] = f2bf(tile[tn][nn]);
  }
}

// ---------------- fp32 -> bf16 weight pack ----------------
__global__ __launch_bounds__(256) void pack_bf16_k(const float* __restrict__ w,
                                                   unsigned short* __restrict__ o) {
  const int i = (blockIdx.x * 256 + threadIdx.x) * 4;
  const float4 v = *(const float4*)(w + i);
  ushort4 u; u.x = f2bf(v.x); u.y = f2bf(v.y); u.z = f2bf(v.z); u.w = f2bf(v.w);
  *(ushort4*)(o + i) = u;
}

__global__ void pack_bias_k(const float* __restrict__ bq, const float* __restrict__ bk,
                            float* __restrict__ bqk) {
  const int t = threadIdx.x;
  bqk[t] = (t < 512) ? bq[t] : bk[t - 512];
}

// ---------------- per-row 1/L combine from per-tile sums (NT tiles of 128 rows) ----------------
__global__ __launch_bounds__(256) void combine_k(const float* __restrict__ rs,
                                                 float* __restrict__ linv, int ntile) {
  const int row = blockIdx.x * 256 + threadIdx.x;  // [0, 18432)
  const int t = row / 2304, r = row % 2304;
  float L = 0.f;
  for (int x = 0; x < ntile; ++x) L += rs[((long)(t * ntile + x)) * 2304 + r];
  linv[row] = 1.0f / L;
}

// ================= BMx256x64 NT GEMM, XCD-swizzled, bf16/fp8 =================
// C[n*ldc+m] = alpha*sum_k A[m,k]*B[n,k] (+bias)(+resid)
// BM=256: 512 thr, 8 waves (2m x 4n), 1 block/CU. setprio(1) around MFMA kept:
//   T5-positive regime (lockstep waves, single block).
// BM=128: 256 thr, 4 waves (1m x 4n); fp8 -> 48KB LDS, ~224 regs/wave ->
//   2 blocks/CU co-resident: independent barrier groups overlap each other's
//   stage/vmcnt stalls.
//   R11: NO setprio on this path. Theory: prio-1 MFMA waves (issue-ready every
//   ~5cy) starve the sibling block's prio-0 waves out of the dead issue slots
//   they need for stage/ds_read/VALU -- co-blocks alternate instead of overlap.
//   (R10's barrier-halving null ruled out barrier count; setprio is shared by
//   both variants and is the remaining cross-block coupling.)
// P2=0 (8-phase snake): (m0,n0)->(m0,n1)->(m1,n1)->(m1,n0); A-half reused 2 phases.
//   Stages: p0:A0(W+1)->s^1  p1:B1(W+1)->s^1  p2:B0(W+2)->s  p3:A1(W+2)->s.
//   Prologue: [B0(0),A0(0),B1(0),A1(0),B0(1),A1(1)].
//   vmcnt (gll units): V0=GB+2GA @p0-end, V3=2GB+GA @p3-end, VP=GB+GA prologue.
// P2=1 (2-phase, 4 barriers/K-step):
//   P0: read A0,B0,B1; stage [A0,B1,A1](W+1)->s^1 (A1 LAST); mfma (m0 x n0,n1).
//   P1: read A1; stage B0(W+2)->s; mfma (m1 x n1,n0).
//   FIFO-derived waits: @P0-end vmcnt(2GA+2GB) (drains A1(W)); @P1-end vmcnt(GA+GB);
//   tail: P1-end GA when st2 off, 0 last.
//   Prologue: [B0(0),A0(0),B1(0),A1(0),B0(1)]  (A1(1) moves into W0-P0 trio).
//   Hazard note: A1(W+2) may NOT be staged in the same phase that reads A1(W).
// STATS scratch: NSLOT = waves-per-n-column (8 for BM=256, 4 for BM=128).
// OUT_MODE: 0 bf16, 1 f32+resid, 2 fp8 e4m3 k-interleaved. STATS: exp+rowsums.
// SCALEN: *linv[n]. MODE0: bz=bid%8 per XCD; MODE1/2: XCD y/x-chunking.
template <int BM, int BIAS_MODE, int OUT_MODE, int STATS, int SCALEN, int MODE, int FP8, int P2>
__global__ __launch_bounds__(512, 2) void gemm256(const void* __restrict__ A, long lda, long sAz,
                                                  const void* __restrict__ B, long ldb, long sBz,
                                                  void* __restrict__ Cp, long ldc, long sCz,
                                                  const float* __restrict__ bias,
                                                  const float* __restrict__ resid,
                                                  float* __restrict__ rowsums,
                                                  const float* __restrict__ linv,
                                                  float alpha, int K, int gx, int gy) {
  constexpr int EB = FP8 ? 1 : 2;                    // element bytes
  constexpr int THREADS = (BM == 256) ? 512 : 256;
  constexpr int HBA = (BM / 2) * 64 * EB;            // bytes per A half
  constexpr int HBB = 128 * 64 * EB;                 // bytes per B half
  constexpr int GA = HBA / (THREADS * 16);           // gll per A-half stage
  constexpr int GB = HBB / (THREADS * 16);           // gll per B-half stage
  constexpr int V0 = GB + 2 * GA, V3 = 2 * GB + GA, VP = GB + GA;
  constexpr int NSLOT = (BM == 256) ? 8 : 4;
  constexpr int PRIO = !P2;                          // R11: no setprio for 2-block path
  __shared__ alignas(16) unsigned char As[2][2][HBA];
  __shared__ alignas(16) unsigned char Bs[2][2][HBB];
  using ABt2 = typename std::conditional<FP8, longx2, bf2frag>::type;

  const int tid = threadIdx.x;
  const int lane = tid & 63, wid = tid >> 6;
  const int wm = (BM == 256) ? (wid & 1) : 0;
  const int wn = (BM == 256) ? (wid >> 1) : wid;
  int bx, by, bz;
  {
    const int g8 = blockIdx.x & 7, n = blockIdx.x >> 3;
    if (MODE == 0) { bz = g8; bx = n % gx; by = n / gx; }
    else if (MODE == 1) { bz = 0; bx = n % gx; by = g8 * gy + n / gx; }
    else { bz = 0; by = n % gy; bx = g8 * gx + n / gy; }
  }
  const unsigned char* Ab = (const unsigned char*)A + ((long)bz * sAz + (long)bx * BM * lda) * EB;
  const unsigned char* Bb = (const unsigned char*)B + ((long)bz * sBz + (long)by * 256 * ldb) * EB;

  // ---- staging (global -> LDS, pre-swizzled source; fp8 global is k-interleaved) ----
  auto stageA = [&](int slot, int h, int k0) {
    if constexpr (!FP8) {
      const int ksw = ((tid & 7) << 3) ^ (((tid >> 3) & 7) << 3);
#pragma unroll
      for (int call = 0; call < GA; ++call) {
        const int r = call * (THREADS / 8) + (tid >> 3);
        const int grow = ((r >> 6) << 7) + h * 64 + (r & 63);
        gll(Ab + ((long)grow * lda + k0) * 2 + ksw * 2, &As[slot][h][call * THREADS * 16 + tid * 16]);
      }
    } else {
#pragma unroll
      for (int call = 0; call < GA; ++call) {
        const int l = call * (THREADS / 4) + (tid >> 2);
        const int grow = ((l >> 6) << 7) + h * 64 + (l & 63);
        const int x = (((l & 3) ^ ((l >> 2) & 3)) << 4);
        gll(Ab + (long)grow * lda + k0 + (((tid & 3) << 4) ^ x),
            &As[slot][h][call * THREADS * 16 + tid * 16]);
      }
    }
  };
  auto stageB = [&](int slot, int h, int k0) {
    if constexpr (!FP8) {
      const int ksw = ((tid & 7) << 3) ^ (((tid >> 3) & 7) << 3);
#pragma unroll
      for (int call = 0; call < GB; ++call) {
        const int r = call * (THREADS / 8) + (tid >> 3);
        const int grow = ((r >> 5) << 6) + h * 32 + (r & 31);
        gll(Bb + ((long)grow * ldb + k0) * 2 + ksw * 2, &Bs[slot][h][call * THREADS * 16 + tid * 16]);
      }
    } else {
#pragma unroll
      for (int call = 0; call < GB; ++call) {
        const int l = call * (THREADS / 4) + (tid >> 2);
        const int grow = ((l >> 5) << 6) + h * 32 + (l & 31);
        const int x = (((l & 3) ^ ((l >> 2) & 3)) << 4);
        gll(Bb + (long)grow * ldb + k0 + (((tid & 3) << 4) ^ x),
            &Bs[slot][h][call * THREADS * 16 + tid * 16]);
      }
    }
  };
  // ---- LDS -> fragment reads (same swizzle; fp8 = ONE b128 for both k2 slices) ----
  auto ldA = [&](int slot, int mh, int fq) -> ABt2 {
    const int r = wm * 64 + fq * 16 + (lane & 15);
    if constexpr (!FP8) {
      bf2frag f;
      const int kk0 = (((lane >> 4) << 3)) ^ ((r & 7) << 3);
      const int kk1 = (32 + ((lane >> 4) << 3)) ^ ((r & 7) << 3);
      f.k0 = *reinterpret_cast<const bf16x8*>(&As[slot][mh][r * 128 + kk0 * 2]);
      f.k1 = *reinterpret_cast<const bf16x8*>(&As[slot][mh][r * 128 + kk1 * 2]);
      return f;
    } else {
      const int x = (((r & 3) ^ ((r >> 2) & 3)) << 4);
      const int kk = ((lane >> 4) << 4) ^ x;
      return *reinterpret_cast<const longx2*>(&As[slot][mh][r * 64 + kk]);
    }
  };
  auto ldB = [&](int slot, int nh, int g) -> ABt2 {
    const int r = wn * 32 + g * 16 + (lane & 15);
    if constexpr (!FP8) {
      bf2frag f;
      const int kk0 = (((lane >> 4) << 3)) ^ ((r & 7) << 3);
      const int kk1 = (32 + ((lane >> 4) << 3)) ^ ((r & 7) << 3);
      f.k0 = *reinterpret_cast<const bf16x8*>(&Bs[slot][nh][r * 128 + kk0 * 2]);
      f.k1 = *reinterpret_cast<const bf16x8*>(&Bs[slot][nh][r * 128 + kk1 * 2]);
      return f;
    } else {
      const int x = (((r & 3) ^ ((r >> 2) & 3)) << 4);
      const int kk = ((lane >> 4) << 4) ^ x;
      return *reinterpret_cast<const longx2*>(&Bs[slot][nh][r * 64 + kk]);
    }
  };

  f32x4 acc[8][4] = {};
  ABt2 a[4], b0[2], b1[2];

#define READ_A(SLOT, MH)                                                     \
  _Pragma("unroll") for (int fq = 0; fq < 4; ++fq) a[fq] = ldA(SLOT, MH, fq);
#define READ_B(SLOT, NH, DST)                                                \
  _Pragma("unroll") for (int g = 0; g < 2; ++g) DST[g] = ldB(SLOT, NH, g);
#define MFMA_QUAD(MH, NH, BARR)                                              \
  if constexpr (PRIO) __builtin_amdgcn_s_setprio(1);                         \
  _Pragma("unroll") for (int fq = 0; fq < 4; ++fq)                           \
    _Pragma("unroll") for (int g = 0; g < 2; ++g)                            \
      _Pragma("unroll") for (int k2 = 0; k2 < 2; ++k2)                       \
        acc[(MH) * 4 + fq][(NH) * 2 + g] =                                   \
            mmak(a[fq], BARR[g], acc[(MH) * 4 + fq][(NH) * 2 + g], k2);      \
  if constexpr (PRIO) __builtin_amdgcn_s_setprio(0);

  const int KT = K >> 6;
  // Prologue queue: [B0(0), A0(0), B1(0), A1(0), B0(1)] (+A1(1) for P2=0)
  stageB(0, 0, 0);
  stageA(0, 0, 0);
  stageB(0, 1, 0);
  stageA(0, 1, 0);
  stageB(1, 0, 64);
  if constexpr (!P2) stageA(1, 1, 64);
  vmw<VP>();
  bar();

  if constexpr (!P2) {
    for (int W = 0; W < KT; ++W) {
      const int s = W & 1;
      const int kn1 = (W + 1) << 6, kn2 = (W + 2) << 6;
      const bool st1 = (W + 1 < KT), st2 = (W + 2 < KT);
      // p0: (m0,n0)
      READ_A(s, 0)
      READ_B(s, 0, b0)
      if (st1) stageA(s ^ 1, 0, kn1);
      bar();
      MFMA_QUAD(0, 0, b0)
      if (st1) { vmw<V0>(); }
      bar();
      // p1: (m0,n1)
      READ_B(s, 1, b1)
      if (st1) stageB(s ^ 1, 1, kn1);
      bar();
      MFMA_QUAD(0, 1, b1)
      bar();
      // p2: (m1,n1)
      READ_A(s, 1)
      if (st2) stageB(s, 0, kn2);
      bar();
      MFMA_QUAD(1, 1, b1)
      bar();
      // p3: (m1,n0)
      if (st2) stageA(s, 1, kn2);
      bar();
      MFMA_QUAD(1, 0, b0)
      if (st2) { vmw<V3>(); } else { vmw<0>(); }
      bar();
    }
  } else {
    for (int W = 0; W < KT; ++W) {
      const int s = W & 1;
      const int kn1 = (W + 1) << 6, kn2 = (W + 2) << 6;
      const bool st1 = (W + 1 < KT), st2 = (W + 2 < KT);
      // P0: (m0 x n0,n1); stage next A-slot fully + B1(W+1). A1 issued LAST.
      READ_A(s, 0)
      READ_B(s, 0, b0)
      READ_B(s, 1, b1)
      if (st1) { stageA(s ^ 1, 0, kn1); stageB(s ^ 1, 1, kn1); stageA(s ^ 1, 1, kn1); }
      bar();
      MFMA_QUAD(0, 0, b0)
      MFMA_QUAD(0, 1, b1)
      if (st1) { vmw<2 * (GA + GB)>(); } else { vmw<0>(); }
      bar();
      // P1: (m1 x n1,n0); stage B0(W+2) into current slot (B0(W) consumed in P0).
      READ_A(s, 1)
      if (st2) stageB(s, 0, kn2);
      bar();
      MFMA_QUAD(1, 1, b1)
      MFMA_QUAD(1, 0, b0)
      if (st2) { vmw<GA + GB>(); } else if (st1) { vmw<GA>(); } else { vmw<0>(); }
      bar();
    }
  }

  // epilogue: acc[M][N], M = mh*4+fq (m-off = mh*64+fq*16), N = nh*2+g
  const int mg0 = bx * BM + wm * 128 + ((lane >> 4) << 2);
  const int ng0 = by * 256 + wn * 64 + (lane & 15);
  float* red = (float*)&As[0][0][0];  // STATS scratch: 256 rows x NSLOT f32
#pragma unroll
  for (int N = 0; N < 4; ++N) {
    const int n = ng0 + (N >> 1) * 32 + (N & 1) * 16;
    const float bn = (BIAS_MODE == 2) ? bias[n] : 0.f;
    const float sc = SCALEN ? linv[(long)bz * 2304 + n] : 1.0f;
    float eN = 0.f;
#pragma unroll
    for (int M = 0; M < 8; ++M) {
      const int m = mg0 + (M >> 2) * 64 + (M & 3) * 16;
      const f32x4 av = acc[M][N];
      float vals[4];
#pragma unroll
      for (int j = 0; j < 4; ++j) {
        vals[j] = av[j] * alpha + ((BIAS_MODE == 1) ? bias[m + j] : bn);
        if (SCALEN) vals[j] *= sc;
        if (STATS) { vals[j] = __expf(vals[j]); eN += vals[j]; }
      }
      if (OUT_MODE == 0) {
        ushort4 o; o.x = f2bf(vals[0]); o.y = f2bf(vals[1]); o.z = f2bf(vals[2]); o.w = f2bf(vals[3]);
        *(ushort4*)((unsigned short*)Cp + (long)bz * sCz + (long)n * ldc + m) = o;
      } else if (OUT_MODE == 2) {
        int pk = __builtin_amdgcn_cvt_pk_fp8_f32(vals[0], vals[1], 0, false);
        pk = __builtin_amdgcn_cvt_pk_fp8_f32(vals[2], vals[3], pk, true);
        *(int*)((unsigned char*)Cp + (long)bz * sCz + (long)n * ldc + perm64(m)) = pk;
      } else {
        const float* rp = resid + (long)n * ldc + m;
        float4 o; o.x = vals[0] + rp[0]; o.y = vals[1] + rp[1]; o.z = vals[2] + rp[2]; o.w = vals[3] + rp[3];
        *(float4*)((float*)Cp + (long)bz * sCz + (long)n * ldc + m) = o;
      }
    }
    if (STATS) {
      const int nloc = wn * 64 + (N >> 1) * 32 + (N & 1) * 16 + (lane & 15);
      const int slot = wm * 4 + (lane >> 4);
      red[nloc * NSLOT + slot] = eN;
    }
  }
  if (STATS) {
    bar();
    if (tid < 256) {
      float L = 0.f;
#pragma unroll
      for (int s2 = 0; s2 < NSLOT; ++s2) L += red[tid * NSLOT + s2];
      rowsums[((long)(bz * gx + bx)) * 2304 + by * 256 + tid] = L;
    }
  }
#undef READ_A
#undef READ_B
#undef MFMA_QUAD
}

extern "C" void kernel_launch(void* const* d_in, const int* in_sizes, int n_in,
                              void* d_out, int out_size, void* d_ws, size_t ws_size,
                              hipStream_t stream) {
  const float* x = (const float*)d_in[0];
  const float* gamma = (const float*)d_in[1];
  const float* beta = (const float*)d_in[2];
  const float* wq = (const float*)d_in[3];
  const float* bq = (const float*)d_in[4];
  const float* wk = (const float*)d_in[5];
  const float* bk = (const float*)d_in[6];
  const float* wv = (const float*)d_in[7];
  const float* bv = (const float*)d_in[8];
  const float* wo = (const float*)d_in[9];
  const float* bo = (const float*)d_in[10];
  float* out = (float*)d_out;

  char* ws = (char*)d_ws;
  size_t off = 0;
  auto alloc = [&](size_t bytes) {
    char* p = ws + off;
    off = (off + bytes + 255) & ~(size_t)255;
    return p;
  };
  float* part = (float*)alloc(256 * 2 * sizeof(float));
  float* stats = (float*)alloc(32 * 2 * sizeof(float));
  unsigned short* wqkb = (unsigned short*)alloc((size_t)2 * 262144 * 2);
  unsigned short* wvb = (unsigned short*)alloc((size_t)262144 * 2);
  unsigned short* wob = (unsigned short*)alloc((size_t)262144 * 2);
  float* bqk = (float*)alloc(1024 * sizeof(float));
  float* rowsums = (float*)alloc((size_t)8 * 18 * 2304 * sizeof(float));
  float* linv = (float*)alloc((size_t)18432 * sizeof(float));
  unsigned short* hnT = (unsigned short*)alloc((size_t)18432 * 512 * 2);
  unsigned char* qkA = (unsigned char*)alloc((size_t)18432 * 1024);      // fp8 k-interleaved
  unsigned char* vT = (unsigned char*)alloc((size_t)512 * 18432);        // fp8 k-interleaved
  unsigned char* Sm = (unsigned char*)alloc((size_t)8 * 2304 * 2304);    // fp8 E k-interleaved
  unsigned short* Ob = hnT;  // alias: hnT fully consumed after qk/v GEMMs
  (void)ws_size; (void)in_sizes; (void)n_in; (void)out_size;

  stats_partial_k<<<dim3(256), dim3(256), 0, stream>>>(x, part);
  stats_final_k<<<dim3(1), dim3(64), 0, stream>>>(part, stats);
  gn_transpose_k<<<dim3(8, 288), dim3(256), 0, stream>>>(x, stats, gamma, beta, hnT);
  pack_bf16_k<<<dim3(256), dim3(256), 0, stream>>>(wq, wqkb);
  pack_bf16_k<<<dim3(256), dim3(256), 0, stream>>>(wk, wqkb + 262144);
  pack_bf16_k<<<dim3(256), dim3(256), 0, stream>>>(wv, wvb);
  pack_bf16_k<<<dim3(256), dim3(256), 0, stream>>>(wo, wob);
  pack_bias_k<<<dim3(1), dim3(1024), 0, stream>>>(bq, bk, bqk);

  // qk fused: A=[Wq;Wk] bf16, B=hnT bf16 -> q,k fp8 interleaved [sp][1024]. MODE1: 288 blocks.
  gemm256<256, 1, 2, 0, 0, 1, 0, 0><<<dim3(288), dim3(512), 0, stream>>>(
      wqkb, 512, 0, hnT, 512, 0, (void*)qkA, 1024, 0, bqk, nullptr, nullptr, nullptr,
      1.0f, 512, 4, 9);
  // v: A=hnT bf16, B=Wv bf16 -> vT fp8 interleaved [co][18432]. MODE2: 144 blocks.
  gemm256<256, 2, 2, 0, 0, 2, 0, 0><<<dim3(144), dim3(512), 0, stream>>>(
      hnT, 512, 0, wvb, 512, 0, (void*)vT, 18432, 0, bv, nullptr, nullptr, nullptr,
      1.0f, 512, 9, 2);
  // S: per t: A=k fp8, B=q fp8 -> E=exp(alpha*S) fp8 interleaved + rowsums.
  // BM=128 (256 thr, 2 blocks/CU), P2=1 (no setprio): 1296 blocks MODE0.
  gemm256<128, 0, 2, 1, 0, 0, 1, 1><<<dim3(1296), dim3(256), 0, stream>>>(
      qkA + 512, 1024, (long)2304 * 1024, qkA, 1024, (long)2304 * 1024, (void*)Sm, 2304,
      (long)2304 * 2304, nullptr, nullptr, rowsums, nullptr,
      0.044194173824159216f, 512, 18, 9);
  combine_k<<<dim3(72), dim3(256), 0, stream>>>(rowsums, linv, 18);
  // PV: per t: A=vT fp8, B=E fp8 -> O bf16 [(t,i)*512+c], rows scaled by linv.
  // BM=128 (256 thr, 2 blocks/CU), P2=1 (no setprio): 288 blocks MODE0.
  gemm256<128, 0, 0, 0, 1, 0, 1, 1><<<dim3(288), dim3(256), 0, stream>>>(
      vT, 18432, 2304, Sm, 2304, (long)2304 * 2304, (void*)Ob, 512, (long)2304 * 512,
      nullptr, nullptr, nullptr, linv, 1.0f, 2304, 4, 0);
  // final: A=O bf16, B=Wo bf16 -> out[co*18432+sp] = x + acc + bo[co]. MODE2: 144 blocks.
  gemm256<256, 2, 1, 0, 0, 2, 0, 0><<<dim3(144), dim3(512), 0, stream>>>(
      Ob, 512, 0, wob, 512, 0, (void*)out, 18432, 0, bo, x, nullptr, nullptr,
      1.0f, 512, 9, 2);
}